// Round 4
// baseline (4218.858 us; speedup 1.0000x reference)
//
#include <hip/hip_runtime.h>
#include <hip/hip_bf16.h>

// FP8Linear: emulated-fp8 quantize (scale=1) of x[M,K] and w[N,K], then
// out[M,N] = Xq @ Wq^T + bias, f32.
// Quantized values have <=4 significant bits -> exact in bf16.
// Pass 1: quantize f32 -> bf16 into d_ws.
// Pass 2: bf16 MFMA GEMM, 256x256 tile, BK=64, 8 waves (2Mx4N), 2-dbuf
// 128KB LDS. REGISTER staging (global->VGPR at P1, swizzled ds_write_b128 at
// P4) instead of global_load_lds: avoids the compiler's conservative
// vmcnt(0)-before-ds_read for LDS-DMA aliasing; compiler emits precise
// per-register waits. XOR-swizzled LDS, setprio MFMA clusters, XCD swizzle.

typedef short bf16x8 __attribute__((ext_vector_type(8)));
typedef float f32x4 __attribute__((ext_vector_type(4)));

#define BM 256
#define BN 256
#define BK 64

__device__ __forceinline__ unsigned short quant1(float v) {
    float s = fminf(fmaxf(v, -448.0f), 448.0f);
    float e = floorf(log2f(fabsf(s) + 1e-10f));
    float m = exp2f(e - 3.0f);
    float q = rintf(s / m) * m;
    return (unsigned short)(__float_as_uint(q) >> 16);  // exact: <=4 sig bits
}

__global__ __launch_bounds__(256) void quant_kernel(
    const float4* __restrict__ in, ushort4* __restrict__ out, int n4) {
    int i = blockIdx.x * blockDim.x + threadIdx.x;
    if (i >= n4) return;
    float4 v = in[i];
    ushort4 r;
    r.x = quant1(v.x);
    r.y = quant1(v.y);
    r.z = quant1(v.z);
    r.w = quant1(v.w);
    out[i] = r;
}

// Swizzled fragment read: logical (row,col) -> lds[row*64 + (col ^ sw)],
// sw = (lane&7)<<3 (== (row&7)<<3 for all fragment rows: row = base16 + rl).
__device__ __forceinline__ bf16x8 frag_ld(const short* base, int row, int col, int sw) {
    return *(const bf16x8*)(base + (row << 6) + (col ^ sw));
}

__device__ __forceinline__ void load_af(bf16x8 (&af)[2][2], const short* Ab,
                                        int rbase, int kg, int sw) {
#pragma unroll
    for (int mi = 0; mi < 2; ++mi)
#pragma unroll
        for (int kk = 0; kk < 2; ++kk)
            af[mi][kk] = frag_ld(Ab, rbase + mi * 16, kk * 32 + kg, sw);
}

template <int MBASE>
__device__ __forceinline__ void mfma_quad(f32x4 (&acc)[8][4], const bf16x8 (&af)[2][2],
                                          const bf16x8 (&bfr)[4][2]) {
#pragma unroll
    for (int mi = 0; mi < 2; ++mi)
#pragma unroll
        for (int n = 0; n < 4; ++n)
#pragma unroll
            for (int kk = 0; kk < 2; ++kk)
                acc[MBASE + mi][n] = __builtin_amdgcn_mfma_f32_16x16x32_bf16(
                    af[mi][kk], bfr[n][kk], acc[MBASE + mi][n], 0, 0, 0);
}

#define LGKM0_SB                                         \
    asm volatile("s_waitcnt lgkmcnt(0)" ::: "memory");   \
    __builtin_amdgcn_sched_barrier(0)

// A: Xq [M][K], B: Wq [N][K] (bf16 as short), C: [M][N] f32
__global__ __launch_bounds__(512, 2) void gemm8p(
    const short* __restrict__ A, const short* __restrict__ B,
    const float* __restrict__ bias, float* __restrict__ C,
    int M, int N, int K) {
    extern __shared__ short lds[];  // 2 bufs x (A 16384 + B 16384) shorts = 128KB

    const int tid = threadIdx.x;
    const int lane = tid & 63;
    const int wave = tid >> 6;
    const int wr = wave >> 2;   // 0..1 -> 128 rows each
    const int wc = wave & 3;    // 0..3 -> 64 cols each

    // XCD-aware bijective block swizzle (nwg % 8 == 0)
    const int nwg = gridDim.x;
    const int per = nwg >> 3;
    const int bid = blockIdx.x;
    const int wg = (bid & 7) * per + (bid >> 3);
    const int mtiles = M / BM;
    const int bm = wg % mtiles;
    const int bn = wg / mtiles;

    const int arow0 = bm * BM, brow0 = bn * BN;
    const int NT = K / BK;

    const int rl = lane & 15;
    const int kg = (lane >> 4) << 3;
    const int sw = (lane & 7) << 3;
    const int arb = wr * 128 + rl;
    const int brb = wc * 64 + rl;

    const short* const Aglob = A + (size_t)arow0 * K;
    const short* const Bglob = B + (size_t)brow0 * K;

    // reg-staging addressing: chunk c covers row c*64+srow, cols scol..scol+7
    const int srow = tid >> 3;          // 0..63
    const int scol = (tid & 7) * 8;     // linear global col -> coalesced loads
    const int sdst = scol ^ ((srow & 7) << 3);  // swizzled LDS col

    f32x4 acc[8][4] = {};
    int4 ar[4], br[4];

    auto issue_loads = [&](int kt) {
#pragma unroll
        for (int c = 0; c < 4; ++c)
            ar[c] = *(const int4*)(Aglob + (size_t)(c * 64 + srow) * K + kt + scol);
#pragma unroll
        for (int c = 0; c < 4; ++c)
            br[c] = *(const int4*)(Bglob + (size_t)(c * 64 + srow) * K + kt + scol);
    };
    auto write_lds = [&](short* An, short* Bn) {
#pragma unroll
        for (int c = 0; c < 4; ++c)
            *(int4*)(An + (c * 64 + srow) * 64 + sdst) = ar[c];
#pragma unroll
        for (int c = 0; c < 4; ++c)
            *(int4*)(Bn + (c * 64 + srow) * 64 + sdst) = br[c];
    };

    // ---- prologue: stage tile 0 into buf 0 via regs
    issue_loads(0);
    write_lds(lds, lds + 16384);
    LGKM0_SB;
    __builtin_amdgcn_s_barrier();

    for (int t = 0; t < NT; ++t) {
        const int cur = t & 1;
        const short* Ab = lds + cur * 32768;
        const short* Bb = Ab + 16384;
        short* An = lds + (cur ^ 1) * 32768;
        short* Bn = An + 16384;
        const bool pf = (t + 1 < NT);

        bf16x8 bfr[4][2];
        bf16x8 af[2][2];

        // ---- P1: issue next-tile global loads; read all B frags + A m0-1
        if (pf) issue_loads((t + 1) * BK);
#pragma unroll
        for (int n = 0; n < 4; ++n)
#pragma unroll
            for (int kk = 0; kk < 2; ++kk)
                bfr[n][kk] = frag_ld(Bb, brb + n * 16, kk * 32 + kg, sw);
        load_af(af, Ab, arb + 0 * 16, kg, sw);
        __builtin_amdgcn_s_barrier();
        LGKM0_SB;
        __builtin_amdgcn_s_setprio(1);
        mfma_quad<0>(acc, af, bfr);
        __builtin_amdgcn_s_setprio(0);
        __builtin_amdgcn_s_barrier();

        // ---- P2: A m2-3
        load_af(af, Ab, arb + 2 * 16, kg, sw);
        __builtin_amdgcn_s_barrier();
        LGKM0_SB;
        __builtin_amdgcn_s_setprio(1);
        mfma_quad<2>(acc, af, bfr);
        __builtin_amdgcn_s_setprio(0);
        __builtin_amdgcn_s_barrier();

        // ---- P3: A m4-5
        load_af(af, Ab, arb + 4 * 16, kg, sw);
        __builtin_amdgcn_s_barrier();
        LGKM0_SB;
        __builtin_amdgcn_s_setprio(1);
        mfma_quad<4>(acc, af, bfr);
        __builtin_amdgcn_s_setprio(0);
        __builtin_amdgcn_s_barrier();

        // ---- P4: A m6-7; write staged regs into other buf (precise vmcnt
        //          inserted by compiler per-register); lgkm drain hides
        //          under MFMA; closing barrier publishes for next P1.
        load_af(af, Ab, arb + 6 * 16, kg, sw);
        __builtin_amdgcn_s_barrier();
        if (pf) write_lds(An, Bn);
        LGKM0_SB;
        __builtin_amdgcn_s_setprio(1);
        mfma_quad<6>(acc, af, bfr);
        __builtin_amdgcn_s_setprio(0);
        __builtin_amdgcn_s_barrier();
    }

    // epilogue: D row = (lane>>4)*4 + j (A side), col = lane&15 (B side)
    const int rg = (lane >> 4) * 4;
#pragma unroll
    for (int n = 0; n < 4; ++n) {
        int col = brow0 + wc * 64 + n * 16 + rl;
        float bv = bias[col];
#pragma unroll
        for (int m = 0; m < 8; ++m) {
            int rowb = arow0 + wr * 128 + m * 16 + rg;
#pragma unroll
            for (int j = 0; j < 4; ++j)
                C[(size_t)(rowb + j) * N + col] = acc[m][n][j] + bv;
        }
    }
}

extern "C" void kernel_launch(void* const* d_in, const int* in_sizes, int n_in,
                              void* d_out, int out_size, void* d_ws, size_t ws_size,
                              hipStream_t stream) {
    const float* x = (const float*)d_in[0];     // [M,K]
    const float* w = (const float*)d_in[1];     // [N,K]
    const float* bias = (const float*)d_in[2];  // [N]
    float* out = (float*)d_out;

    const int N = in_sizes[2];                 // 16384
    const int K = in_sizes[1] / N;             // 4096
    const int M = in_sizes[0] / K;             // 8192

    short* xq = (short*)d_ws;
    short* wq = xq + (size_t)M * K;

    int nx4 = M * K / 4;
    int nw4 = N * K / 4;
    quant_kernel<<<(nx4 + 255) / 256, 256, 0, stream>>>(
        (const float4*)x, (ushort4*)xq, nx4);
    quant_kernel<<<(nw4 + 255) / 256, 256, 0, stream>>>(
        (const float4*)w, (ushort4*)wq, nw4);

    hipFuncSetAttribute((const void*)gemm8p,
                        hipFuncAttributeMaxDynamicSharedMemorySize, 131072);

    int nwg = (M / BM) * (N / BN);  // 32*64 = 2048, %8==0
    gemm8p<<<nwg, 512, 131072, stream>>>(
        (const short*)xq, (const short*)wq, bias, out, M, N, K);
}

// Round 5
// 3523.373 us; speedup vs baseline: 1.1974x; 1.1974x over previous
//
#include <hip/hip_runtime.h>
#include <hip/hip_bf16.h>

// FP8Linear: emulated-fp8 quantize (scale=1) of x[M,K] and w[N,K], then
// out[M,N] = Xq @ Wq^T + bias, f32.
// Quantized values have <=4 significant bits -> exact in bf16.
// Pass 1: quantize f32 -> bf16 into d_ws.
// Pass 2: bf16 MFMA GEMM, 256x256 tile, BK=64, 8 waves (2Mx4N), 2-dbuf
// 128KB LDS. REGISTER staging: global->VGPR issued at P1 (3 phases of HBM
// cover), swizzled ds_write_b128 AFTER P4's MFMA cluster, lgkmcnt(0) before
// the publishing barrier. amdgpu_waves_per_eu(2,2) pins the allocator at the
// 256-VGPR budget (launch_bounds(512,2) was CUDA-min-blocks -> 128 cap ->
// R4's staged regs spilled to scratch: WRITE_SIZE 0.53->4.7GB).
// XOR-swizzled LDS, setprio MFMA clusters, XCD block swizzle.

typedef short bf16x8 __attribute__((ext_vector_type(8)));
typedef float f32x4 __attribute__((ext_vector_type(4)));

#define BM 256
#define BN 256
#define BK 64

__device__ __forceinline__ unsigned short quant1(float v) {
    float s = fminf(fmaxf(v, -448.0f), 448.0f);
    float e = floorf(log2f(fabsf(s) + 1e-10f));
    float m = exp2f(e - 3.0f);
    float q = rintf(s / m) * m;
    return (unsigned short)(__float_as_uint(q) >> 16);  // exact: <=4 sig bits
}

__global__ __launch_bounds__(256) void quant_kernel(
    const float4* __restrict__ in, ushort4* __restrict__ out, int n4) {
    int i = blockIdx.x * blockDim.x + threadIdx.x;
    if (i >= n4) return;
    float4 v = in[i];
    ushort4 r;
    r.x = quant1(v.x);
    r.y = quant1(v.y);
    r.z = quant1(v.z);
    r.w = quant1(v.w);
    out[i] = r;
}

// Swizzled fragment read: logical (row,col) -> lds[row*64 + (col ^ sw)],
// sw = (lane&7)<<3 (== (row&7)<<3 for all fragment rows: row = base16 + rl).
__device__ __forceinline__ bf16x8 frag_ld(const short* base, int row, int col, int sw) {
    return *(const bf16x8*)(base + (row << 6) + (col ^ sw));
}

__device__ __forceinline__ void load_af(bf16x8 (&af)[2][2], const short* Ab,
                                        int rbase, int kg, int sw) {
#pragma unroll
    for (int mi = 0; mi < 2; ++mi)
#pragma unroll
        for (int kk = 0; kk < 2; ++kk)
            af[mi][kk] = frag_ld(Ab, rbase + mi * 16, kk * 32 + kg, sw);
}

template <int MBASE>
__device__ __forceinline__ void mfma_quad(f32x4 (&acc)[8][4], const bf16x8 (&af)[2][2],
                                          const bf16x8 (&bfr)[4][2]) {
#pragma unroll
    for (int mi = 0; mi < 2; ++mi)
#pragma unroll
        for (int n = 0; n < 4; ++n)
#pragma unroll
            for (int kk = 0; kk < 2; ++kk)
                acc[MBASE + mi][n] = __builtin_amdgcn_mfma_f32_16x16x32_bf16(
                    af[mi][kk], bfr[n][kk], acc[MBASE + mi][n], 0, 0, 0);
}

#define LGKM0_SB                                         \
    asm volatile("s_waitcnt lgkmcnt(0)" ::: "memory");   \
    __builtin_amdgcn_sched_barrier(0)

// A: Xq [M][K], B: Wq [N][K] (bf16 as short), C: [M][N] f32
__global__ __launch_bounds__(512)
__attribute__((amdgpu_waves_per_eu(2, 2)))
void gemm8p(
    const short* __restrict__ A, const short* __restrict__ B,
    const float* __restrict__ bias, float* __restrict__ C,
    int M, int N, int K) {
    extern __shared__ short lds[];  // 2 bufs x (A 16384 + B 16384) shorts = 128KB

    const int tid = threadIdx.x;
    const int lane = tid & 63;
    const int wave = tid >> 6;
    const int wr = wave >> 2;   // 0..1 -> 128 rows each
    const int wc = wave & 3;    // 0..3 -> 64 cols each

    // XCD-aware bijective block swizzle (nwg % 8 == 0)
    const int nwg = gridDim.x;
    const int per = nwg >> 3;
    const int bid = blockIdx.x;
    const int wg = (bid & 7) * per + (bid >> 3);
    const int mtiles = M / BM;
    const int bm = wg % mtiles;
    const int bn = wg / mtiles;

    const int arow0 = bm * BM, brow0 = bn * BN;
    const int NT = K / BK;

    const int rl = lane & 15;
    const int kg = (lane >> 4) << 3;
    const int sw = (lane & 7) << 3;
    const int arb = wr * 128 + rl;
    const int brb = wc * 64 + rl;

    const short* const Aglob = A + (size_t)arow0 * K;
    const short* const Bglob = B + (size_t)brow0 * K;

    // reg-staging addressing: chunk c covers row c*64+srow, cols scol..scol+7
    const int srow = tid >> 3;          // 0..63
    const int scol = (tid & 7) * 8;     // linear global col -> coalesced loads
    const int sdst = scol ^ ((srow & 7) << 3);  // swizzled LDS col

    f32x4 acc[8][4] = {};
    int4 ar[4], br[4];

    auto issue_loads = [&](int kt) {
#pragma unroll
        for (int c = 0; c < 4; ++c)
            ar[c] = *(const int4*)(Aglob + (size_t)(c * 64 + srow) * K + kt + scol);
#pragma unroll
        for (int c = 0; c < 4; ++c)
            br[c] = *(const int4*)(Bglob + (size_t)(c * 64 + srow) * K + kt + scol);
    };
    auto write_lds = [&](short* An, short* Bn) {
#pragma unroll
        for (int c = 0; c < 4; ++c)
            *(int4*)(An + (c * 64 + srow) * 64 + sdst) = ar[c];
#pragma unroll
        for (int c = 0; c < 4; ++c)
            *(int4*)(Bn + (c * 64 + srow) * 64 + sdst) = br[c];
    };

    // ---- prologue: stage tile 0 into buf 0 via regs
    issue_loads(0);
    write_lds(lds, lds + 16384);
    LGKM0_SB;
    __builtin_amdgcn_s_barrier();

    for (int t = 0; t < NT; ++t) {
        const int cur = t & 1;
        const short* Ab = lds + cur * 32768;
        const short* Bb = Ab + 16384;
        short* An = lds + (cur ^ 1) * 32768;
        short* Bn = An + 16384;
        const bool pf = (t + 1 < NT);

        bf16x8 bfr[4][2];
        bf16x8 af[2][2];

        // ---- P1: issue next-tile global loads; read all B frags + A m0-1
        if (pf) issue_loads((t + 1) * BK);
#pragma unroll
        for (int n = 0; n < 4; ++n)
#pragma unroll
            for (int kk = 0; kk < 2; ++kk)
                bfr[n][kk] = frag_ld(Bb, brb + n * 16, kk * 32 + kg, sw);
        load_af(af, Ab, arb + 0 * 16, kg, sw);
        __builtin_amdgcn_s_barrier();
        LGKM0_SB;
        __builtin_amdgcn_s_setprio(1);
        mfma_quad<0>(acc, af, bfr);
        __builtin_amdgcn_s_setprio(0);
        __builtin_amdgcn_s_barrier();

        // ---- P2: A m2-3
        load_af(af, Ab, arb + 2 * 16, kg, sw);
        __builtin_amdgcn_s_barrier();
        LGKM0_SB;
        __builtin_amdgcn_s_setprio(1);
        mfma_quad<2>(acc, af, bfr);
        __builtin_amdgcn_s_setprio(0);
        __builtin_amdgcn_s_barrier();

        // ---- P3: A m4-5
        load_af(af, Ab, arb + 4 * 16, kg, sw);
        __builtin_amdgcn_s_barrier();
        LGKM0_SB;
        __builtin_amdgcn_s_setprio(1);
        mfma_quad<4>(acc, af, bfr);
        __builtin_amdgcn_s_setprio(0);
        __builtin_amdgcn_s_barrier();

        // ---- P4: A m6-7; MFMA first; then write staged regs into other buf
        //          (compiler inserts precise vmcnt before the writes; loads
        //          have had ~3 phases to land). lgkmcnt(0) publishes writes
        //          across the closing barrier for next P1's readers.
        load_af(af, Ab, arb + 6 * 16, kg, sw);
        __builtin_amdgcn_s_barrier();
        LGKM0_SB;
        __builtin_amdgcn_s_setprio(1);
        mfma_quad<6>(acc, af, bfr);
        __builtin_amdgcn_s_setprio(0);
        if (pf) write_lds(An, Bn);
        asm volatile("s_waitcnt lgkmcnt(0)" ::: "memory");
        __builtin_amdgcn_s_barrier();
    }

    // epilogue: D row = (lane>>4)*4 + j (A side), col = lane&15 (B side)
    const int rg = (lane >> 4) * 4;
#pragma unroll
    for (int n = 0; n < 4; ++n) {
        int col = brow0 + wc * 64 + n * 16 + rl;
        float bv = bias[col];
#pragma unroll
        for (int m = 0; m < 8; ++m) {
            int rowb = arow0 + wr * 128 + m * 16 + rg;
#pragma unroll
            for (int j = 0; j < 4; ++j)
                C[(size_t)(rowb + j) * N + col] = acc[m][n][j] + bv;
        }
    }
}

extern "C" void kernel_launch(void* const* d_in, const int* in_sizes, int n_in,
                              void* d_out, int out_size, void* d_ws, size_t ws_size,
                              hipStream_t stream) {
    const float* x = (const float*)d_in[0];     // [M,K]
    const float* w = (const float*)d_in[1];     // [N,K]
    const float* bias = (const float*)d_in[2];  // [N]
    float* out = (float*)d_out;

    const int N = in_sizes[2];                 // 16384
    const int K = in_sizes[1] / N;             // 4096
    const int M = in_sizes[0] / K;             // 8192

    short* xq = (short*)d_ws;
    short* wq = xq + (size_t)M * K;

    int nx4 = M * K / 4;
    int nw4 = N * K / 4;
    quant_kernel<<<(nx4 + 255) / 256, 256, 0, stream>>>(
        (const float4*)x, (ushort4*)xq, nx4);
    quant_kernel<<<(nw4 + 255) / 256, 256, 0, stream>>>(
        (const float4*)w, (ushort4*)wq, nw4);

    hipFuncSetAttribute((const void*)gemm8p,
                        hipFuncAttributeMaxDynamicSharedMemorySize, 131072);

    int nwg = (M / BM) * (N / BN);  // 32*64 = 2048, %8==0
    gemm8p<<<nwg, 512, 131072, stream>>>(
        (const short*)xq, (const short*)wq, bias, out, M, N, K);
}